// Round 9
// baseline (154.674 us; speedup 1.0000x reference)
//
#include <hip/hip_runtime.h>
#include <math.h>

// DynamicNTXentLoss on MI355X — r6: global_load_lds streaming pipeline.
//
// r1-r5 post-mortem: every register-resident variant pinned at ~45 µs /
// ~2.9 TB/s aggregate with all pipes <35% busy. Compiler caps VGPR at 64
// regardless of launch_bounds, so at most ~4-8 KB/CU of loads are ever in
// flight -> Little's law gives ~5 B/cyc/CU. Fix: stage tiles directly to
// LDS with __builtin_amdgcn_global_load_lds (no VGPR cost per load) and
// keep 8 KB/wave x 10 waves/CU = 80 KB/CU outstanding with counted
// s_waitcnt vmcnt(8) (never 0 in the main loop). Each wave owns its LDS
// privately -> no barriers anywhere.
//
// Tile k = groups (2k, 2k+1) = zjs rows 4k..4k+3 + zis rows 4k..4k+3
// (8 KB). Wave = 2 halves x 32 lanes; half h computes group 2k+h.
// Lane t in [0,32) owns float4s t and t+32 of each 1 KB row.

constexpr int D = 256;

__device__ __forceinline__ float dot4(float4 a, float4 b) {
    return fmaf(a.x, b.x, fmaf(a.y, b.y, fmaf(a.z, b.z, a.w * b.w)));
}

template <int CTRL>
__device__ __forceinline__ float dpp_add(float x) {
    int y = __builtin_amdgcn_update_dpp(0, __float_as_int(x), CTRL, 0xF, 0xF, true);
    return x + __int_as_float(y);
}

// sum across each 32-lane half; all lanes of the half get the total
__device__ __forceinline__ float red32(float x) {
    x = dpp_add<0xB1>(x);   // quad_perm xor1
    x = dpp_add<0x4E>(x);   // quad_perm xor2
    x = dpp_add<0x124>(x);  // row_ror:4
    x = dpp_add<0x128>(x);  // row_ror:8
    x += __shfl_xor(x, 16); // combine the two 16-lane rows of this half
    return x;
}

__device__ __forceinline__ float rowloss(float a, float b, float c,
                                         float s0, float s1, float s2) {
    float m = fmaxf(fmaxf(a, b), c);
    float lse = m + __logf(__expf(a - m) + __expf(b - m) + __expf(c - m));
    return s0 * (lse - a) + s1 * (lse - b) + s2 * (lse - c);
}

#define AS1(p) ((const __attribute__((address_space(1))) void*)(p))
#define AS3(p) ((__attribute__((address_space(3))) void*)(p))

// stage tile k: zjs rows 4k..4k+3 -> buf[0,4KB), zis rows 4k..4k+3 -> buf[4KB,8KB)
// 8 x global_load_lds, each stages one 1 KB row (lane*16B, linear dest).
__device__ __forceinline__ void stage_tile(const float* __restrict__ zjs,
                                           const float* __restrict__ zis,
                                           int k, char* buf, int lane) {
    const float* sj = zjs + (size_t)k * (4 * D) + lane * 4;
    const float* si = zis + (size_t)k * (4 * D) + lane * 4;
#pragma unroll
    for (int i = 0; i < 4; ++i)
        __builtin_amdgcn_global_load_lds(AS1(sj + i * D), AS3(buf + i * 1024), 16, 0, 0);
#pragma unroll
    for (int i = 0; i < 4; ++i)
        __builtin_amdgcn_global_load_lds(AS1(si + i * D), AS3(buf + 4096 + i * 1024), 16, 0, 0);
}

__global__ __launch_bounds__(64, 2) void ntxent_stage1(
    const float* __restrict__ zis, const float* __restrict__ zjs,
    const float* __restrict__ sl, float* __restrict__ partial, int nc) {
    extern __shared__ __align__(16) char lds[];   // 16384 B: two 8 KB buffers
    const int lane = threadIdx.x;                 // 0..63
    const int h = lane >> 5;                      // half -> group 2k+h
    const int t = lane & 31;

    const int wave  = blockIdx.x;
    const int nwave = gridDim.x;
    const int ntile = (nc + 1) >> 1;

    float L0 = sl[0],  L1 = sl[1],  L2 = sl[2];
    float L3 = sl[3],  L4 = sl[4],  L5 = sl[5];
    float L6 = sl[6],  L7 = sl[7],  L8 = sl[8];
    float L9 = sl[9],  L10 = sl[10], L11 = sl[11];

    float wsum = 0.0f;
    int k = wave;
    if (k < ntile) {
        stage_tile(zjs, zis, k, lds, lane);
        int cur = 0;
        while (true) {
            const int kn = k + nwave;
            const bool more = kn < ntile;
            if (more) {
                stage_tile(zjs, zis, kn, lds + (cur ^ 1) * 8192, lane);
                asm volatile("s_waitcnt vmcnt(8)" ::: "memory");  // cur buffer done
            } else {
                asm volatile("s_waitcnt vmcnt(0)" ::: "memory");
            }

            {
                const float4* bp = (const float4*)(lds + cur * 8192);
                const int r0 = (2 * h) * 64;   // row offsets in float4 units
                const int r1 = r0 + 64;
                const int r2 = 256 + r0;
                const int r3 = r2 + 64;
                float4 a0 = bp[r0 + t], a1 = bp[r0 + 32 + t];
                float4 b0 = bp[r1 + t], b1 = bp[r1 + 32 + t];
                float4 c0 = bp[r2 + t], c1 = bp[r2 + 32 + t];
                float4 e0 = bp[r3 + t], e1 = bp[r3 + 32 + t];

                float n0 = dot4(a0, a0) + dot4(a1, a1);
                float n1 = dot4(b0, b0) + dot4(b1, b1);
                float n2 = dot4(c0, c0) + dot4(c1, c1);
                float n3 = dot4(e0, e0) + dot4(e1, e1);
                float d01 = dot4(a0, b0) + dot4(a1, b1);
                float d02 = dot4(a0, c0) + dot4(a1, c1);
                float d03 = dot4(a0, e0) + dot4(a1, e1);
                float d12 = dot4(b0, c0) + dot4(b1, c1);
                float d13 = dot4(b0, e0) + dot4(b1, e1);
                float d23 = dot4(c0, e0) + dot4(c1, e1);

                n0 = red32(n0);  n1 = red32(n1);  n2 = red32(n2);  n3 = red32(n3);
                d01 = red32(d01); d02 = red32(d02); d03 = red32(d03);
                d12 = red32(d12); d13 = red32(d13); d23 = red32(d23);

                const float i0 = 1.0f / fmaxf(sqrtf(n0), 1e-8f);
                const float i1 = 1.0f / fmaxf(sqrtf(n1), 1e-8f);
                const float i2 = 1.0f / fmaxf(sqrtf(n2), 1e-8f);
                const float i3 = 1.0f / fmaxf(sqrtf(n3), 1e-8f);

                // fold 1/T = 2
                const float s01 = 2.0f * d01 * i0 * i1;
                const float s02 = 2.0f * d02 * i0 * i2;
                const float s03 = 2.0f * d03 * i0 * i3;
                const float s12 = 2.0f * d12 * i1 * i2;
                const float s13 = 2.0f * d13 * i1 * i3;
                const float s23 = 2.0f * d23 * i2 * i3;

                float gl = 0.0f;
                gl += rowloss(s02, s01, s03, L0, L1, L2);
                gl += rowloss(s13, s01, s12, L3, L4, L5);
                gl += rowloss(s02, s12, s23, L6, L7, L8);
                gl += rowloss(s13, s03, s23, L9, L10, L11);

                const bool valid = (2 * k + h) < nc;
                wsum += valid ? gl : 0.0f;
            }

            if (!more) break;
            k = kn;
            cur ^= 1;
        }
    }
    wsum *= (1.0f / 32.0f);   // 32 redundant lanes per group

#pragma unroll
    for (int off = 1; off < 64; off <<= 1) wsum += __shfl_xor(wsum, off);
    if (lane == 0) partial[blockIdx.x] = wsum;
}

__global__ __launch_bounds__(256) void ntxent_stage2(
    const float* __restrict__ partial, int nparts, double inv_div,
    float* __restrict__ out) {
    double acc = 0.0;
    for (int i = threadIdx.x; i < nparts; i += 256) acc += (double)partial[i];
#pragma unroll
    for (int off = 1; off < 64; off <<= 1) acc += __shfl_xor(acc, off);
    __shared__ double sm[4];
    const int wid = threadIdx.x >> 6;
    if ((threadIdx.x & 63) == 0) sm[wid] = acc;
    __syncthreads();
    if (threadIdx.x == 0) out[0] = (float)((sm[0] + sm[1] + sm[2] + sm[3]) * inv_div);
}

extern "C" void kernel_launch(void* const* d_in, const int* in_sizes, int n_in,
                              void* d_out, int out_size, void* d_ws, size_t ws_size,
                              hipStream_t stream) {
    const float* zis = (const float*)d_in[0];
    const float* zjs = (const float*)d_in[1];
    const float* sl  = (const float*)d_in[2];
    float* out = (float*)d_out;
    float* partial = (float*)d_ws;

    const int n  = in_sizes[0] / D;   // 65536 rows
    const int nc = n / 2;             // 32768 groups

    // 2560 x 1-wave blocks, 16 KB LDS each -> 10 waves/CU (LDS-capped),
    // each wave double-buffers 8 KB tiles with counted vmcnt.
    const int blocks = 2560;
    ntxent_stage1<<<blocks, 64, 16384, stream>>>(zis, zjs, sl, partial, nc);

    const double inv_div = 1.0 / (2.0 * (double)n);
    ntxent_stage2<<<1, 256, 0, stream>>>(partial, blocks, inv_div, out);
}

// Round 13
// 150.076 us; speedup vs baseline: 1.0306x; 1.0306x over previous
//
#include <hip/hip_runtime.h>
#include <math.h>

// DynamicNTXentLoss on MI355X — r7: RMSNorm-style streaming, 8 lanes/group.
//
// r1-r6 post-mortem: six structures, all ~45-54 µs at 2.6-3.0 TB/s
// aggregate read, all pipes <35%. Common flaw vs the 4.89 TB/s RMSNorm
// exemplar: a long dependent chain (cross-lane reduce + transcendental
// epilogue, or a wave-serial vmcnt choke) embedded in every few KB of
// loads. r7 removes everything: 8 consecutive lanes own one group; lane s
// reads float4 s+8k of each of the 4 rows (k=0..7, fully unrolled -> 32
// independent perfectly-coalesced loads, 128B-line aligned per team);
// 10 private dot accumulators; ONE 3-step shfl_xor(1,2,4) reduce per
// group (per 4 KB); no LDS staging; 1024 blocks = 16 waves/CU.

constexpr int D = 256;

__device__ __forceinline__ float dot4(float4 a, float4 b) {
    return fmaf(a.x, b.x, fmaf(a.y, b.y, fmaf(a.z, b.z, a.w * b.w)));
}

__device__ __forceinline__ float rowloss(float a, float b, float c,
                                         float s0, float s1, float s2) {
    float m = fmaxf(fmaxf(a, b), c);
    float lse = m + __logf(__expf(a - m) + __expf(b - m) + __expf(c - m));
    return s0 * (lse - a) + s1 * (lse - b) + s2 * (lse - c);
}

// reduce across the 8-lane team (lanes differing in bits 0..2)
__device__ __forceinline__ float red8(float x) {
    x += __shfl_xor(x, 1);
    x += __shfl_xor(x, 2);
    x += __shfl_xor(x, 4);
    return x;
}

__global__ __launch_bounds__(256, 4) void ntxent_stage1(
    const float* __restrict__ zis, const float* __restrict__ zjs,
    const float* __restrict__ sl, float* __restrict__ partial, int nc) {
    const int tid = blockIdx.x * 256 + threadIdx.x;
    const int s   = tid & 7;        // sub-lane within team
    const int g   = tid >> 3;       // group id (one group per 8-lane team)
    const bool valid = g < nc;
    const int gc  = valid ? g : 0;

    const float4* zj4 = (const float4*)zjs;
    const float4* zi4 = (const float4*)zis;

    // row base offsets in float4 units (row = 64 float4)
    const size_t r0 = (size_t)(2 * gc) * 64 + s;   // zjs row 2g
    const size_t r1 = r0 + 64;                     // zjs row 2g+1
    const size_t q0 = (size_t)(2 * gc) * 64 + s;   // zis row 2g
    const size_t q1 = q0 + 64;                     // zis row 2g+1

    float n0 = 0, n1 = 0, n2 = 0, n3 = 0;
    float d01 = 0, d02 = 0, d03 = 0, d12 = 0, d13 = 0, d23 = 0;

#pragma unroll
    for (int k = 0; k < 8; ++k) {
        const float4 a = zj4[r0 + k * 8];
        const float4 b = zj4[r1 + k * 8];
        const float4 c = zi4[q0 + k * 8];
        const float4 e = zi4[q1 + k * 8];
        n0  += dot4(a, a);  n1  += dot4(b, b);
        n2  += dot4(c, c);  n3  += dot4(e, e);
        d01 += dot4(a, b);  d02 += dot4(a, c);
        d03 += dot4(a, e);  d12 += dot4(b, c);
        d13 += dot4(b, e);  d23 += dot4(c, e);
    }

    n0 = red8(n0);  n1 = red8(n1);  n2 = red8(n2);  n3 = red8(n3);
    d01 = red8(d01); d02 = red8(d02); d03 = red8(d03);
    d12 = red8(d12); d13 = red8(d13); d23 = red8(d23);

    const float i0 = 1.0f / fmaxf(sqrtf(n0), 1e-8f);
    const float i1 = 1.0f / fmaxf(sqrtf(n1), 1e-8f);
    const float i2 = 1.0f / fmaxf(sqrtf(n2), 1e-8f);
    const float i3 = 1.0f / fmaxf(sqrtf(n3), 1e-8f);

    // fold 1/T = 2
    const float s01 = 2.0f * d01 * i0 * i1;
    const float s02 = 2.0f * d02 * i0 * i2;
    const float s03 = 2.0f * d03 * i0 * i3;
    const float s12 = 2.0f * d12 * i1 * i2;
    const float s13 = 2.0f * d13 * i1 * i3;
    const float s23 = 2.0f * d23 * i2 * i3;

    float gl = 0.0f;
    gl += rowloss(s02, s01, s03, sl[0], sl[1], sl[2]);
    gl += rowloss(s13, s01, s12, sl[3], sl[4], sl[5]);
    gl += rowloss(s02, s12, s23, sl[6], sl[7], sl[8]);
    gl += rowloss(s13, s03, s23, sl[9], sl[10], sl[11]);

    float wsum = valid ? gl * 0.125f : 0.0f;   // 8 redundant lanes per team

    // wave reduce (teams are disjoint; redundant copies already scaled)
#pragma unroll
    for (int off = 1; off < 64; off <<= 1) wsum += __shfl_xor(wsum, off);

    __shared__ float smem[4];
    const int wid = threadIdx.x >> 6;
    if ((threadIdx.x & 63) == 0) smem[wid] = wsum;
    __syncthreads();
    if (threadIdx.x == 0)
        partial[blockIdx.x] = smem[0] + smem[1] + smem[2] + smem[3];
}

__global__ __launch_bounds__(256) void ntxent_stage2(
    const float* __restrict__ partial, int nparts, double inv_div,
    float* __restrict__ out) {
    double acc = 0.0;
    for (int i = threadIdx.x; i < nparts; i += 256) acc += (double)partial[i];
#pragma unroll
    for (int off = 1; off < 64; off <<= 1) acc += __shfl_xor(acc, off);
    __shared__ double sm[4];
    const int wid = threadIdx.x >> 6;
    if ((threadIdx.x & 63) == 0) sm[wid] = acc;
    __syncthreads();
    if (threadIdx.x == 0) out[0] = (float)((sm[0] + sm[1] + sm[2] + sm[3]) * inv_div);
}

extern "C" void kernel_launch(void* const* d_in, const int* in_sizes, int n_in,
                              void* d_out, int out_size, void* d_ws, size_t ws_size,
                              hipStream_t stream) {
    const float* zis = (const float*)d_in[0];
    const float* zjs = (const float*)d_in[1];
    const float* sl  = (const float*)d_in[2];
    float* out = (float*)d_out;
    float* partial = (float*)d_ws;

    const int n  = in_sizes[0] / D;   // 65536 rows
    const int nc = n / 2;             // 32768 groups

    // one 8-lane team per group: nc*8 threads -> 1024 blocks of 256
    const int blocks = (nc * 8 + 255) / 256;
    ntxent_stage1<<<blocks, 256, 0, stream>>>(zis, zjs, sl, partial, nc);

    const double inv_div = 1.0 / (2.0 * (double)n);
    ntxent_stage2<<<1, 256, 0, stream>>>(partial, blocks, inv_div, out);
}